// Round 16
// baseline (288.906 us; speedup 1.0000x reference)
//
#include <hip/hip_runtime.h>
#include <hip/hip_bf16.h>
#include <math.h>

#define C_DIM 256
#define HWDIM 256
#define CH_STRIDE (HWDIM * HWDIM)      // 65536 floats between channels
#define R_DIM 32
#define XPITCH 65                      // bf162 words per channel row (64 + 1 pad)

// Block = 2 horizontally-adjacent 8x8 patches: region 8 rows x 16 cols x 256 ch
// = 128 pixels/channel = 64 bf162 words (R15's XPITCH=33 overran -> NaN; fixed).
// 512 threads = 8 waves. x staged in LDS as bf16 (xl[256][65] words = 66.5KB,
// pitch 65 = 1 mod 32 -> stage-3 consecutive-c reads conflict-free). Total LDS
// ~77KB -> 2 INDEPENDENT blocks/CU (vs R14's single barrier-locked 1024-thr
// block): one block's stats/pm/MLP phases hide under the other's streaming.
// Per-thread state ~50 VGPR, no big register arrays -> spill-free.
// Reads/writes are 64B segments; the other 64B half of each 128B line belongs
// to the ADJACENT block (same XCD via swizzle, co-resident) -> merges in L2.
// Plain stores (no nt) so half-lines coalesce before writeback.
// LN stats exact-f32 via LDS atomicAdd; values take one bf16 RNE rounding
// (absmax 0.0156 across R5/R9/R14).
__global__
void lpa_fused_kernel(const float* __restrict__ x,
                      const float* __restrict__ gamma,
                      const float* __restrict__ beta,
                      const float* __restrict__ w1,
                      const float* __restrict__ w2,
                      float* __restrict__ out,
                      int nwg)
{
    __shared__ __hip_bfloat162 xl[C_DIM * XPITCH]; // 66,560 B [c][pixel-pair]
    __shared__ float sp1[128];         // per-pixel sum   (atomic, f32-exact)
    __shared__ float sq1[128];         // per-pixel sumsq (atomic, f32-exact)
    __shared__ float mu_s[128];
    __shared__ float rs_s[128];
    __shared__ float gs[C_DIM];
    __shared__ float bs[C_DIM];
    __shared__ float pm_s[2 * C_DIM];  // [patch][c]
    __shared__ float h_s[2 * R_DIM];   // [patch][r]
    __shared__ float2 AB_s[2 * C_DIM]; // [patch][c] = (gamma*gate, beta*gate)

    const int t    = threadIdx.x;
    const int wid  = t >> 6;           // wave 0..7
    const int lane = t & 63;
    const int par  = lane >> 5;        // channel parity within wave
    const int pos  = lane & 31;        // 8 rows x 4 quad-cols
    const int row  = pos >> 2;         // 0..7
    const int qc   = pos & 3;          // float4 col 0..3
    const int pat  = qc >> 1;          // patch 0/1
    const int p0   = row * 16 + qc * 4;   // first pixel (0..127)
    const int p2w  = (p0 >> 1);           // bf162 word index (even, <= 62)

    if (t < 128) { sp1[t] = 0.f; sq1[t] = 0.f; }
    if (t < C_DIM) { gs[t] = gamma[t]; bs[t] = beta[t]; }
    __syncthreads();

    const int bid = blockIdx.x;
    // XCD-aware bijective swizzle (nwg = 4096, multiple of 8): spatially
    // adjacent blocks (which share 128B lines) stay on one XCD's L2.
    const int per_xcd = nwg >> 3;
    const int pid = (bid & 7) * per_xcd + (bid >> 3);

    const int b  = pid >> 9;           // 512 groups per image (32 gh x 16 gw)
    const int ij = pid & 511;
    const unsigned H0 = (unsigned)(ij >> 4) * 8u;
    const unsigned W0 = (unsigned)(ij & 15) * 16u;
    const unsigned rowoff = (unsigned)b * (C_DIM * CH_STRIDE)
                          + (H0 + (unsigned)row) * HWDIM + W0 + (unsigned)qc * 4u;
    const unsigned c0 = (unsigned)wid * 2u + (unsigned)par;  // + k*16 per iter
    const float* xb = x + rowoff + c0 * CH_STRIDE;

    // ---- Stage 1: dense f32 loads -> f32 stats + bf16 LDS staging ----
    float s0 = 0.f, s1 = 0.f, s2 = 0.f, s3 = 0.f;
    float q0 = 0.f, q1 = 0.f, q2 = 0.f, q3 = 0.f;
#pragma unroll
    for (int k = 0; k < 16; ++k) {
        float4 f = *reinterpret_cast<const float4*>(xb + (unsigned)(k * 16) * CH_STRIDE);
        s0 += f.x; q0 += f.x * f.x;
        s1 += f.y; q1 += f.y * f.y;
        s2 += f.z; q2 += f.z * f.z;
        s3 += f.w; q3 += f.w * f.w;
        __hip_bfloat162 lo = __float22bfloat162_rn(make_float2(f.x, f.y));
        __hip_bfloat162 hi = __float22bfloat162_rn(make_float2(f.z, f.w));
        uint2 wv;
        wv.x = *reinterpret_cast<const unsigned*>(&lo);
        wv.y = *reinterpret_cast<const unsigned*>(&hi);
        const int c = (int)c0 + k * 16;
        *reinterpret_cast<uint2*>(&xl[c * XPITCH + p2w]) = wv;
    }
    atomicAdd(&sp1[p0 + 0], s0); atomicAdd(&sq1[p0 + 0], q0);
    atomicAdd(&sp1[p0 + 1], s1); atomicAdd(&sq1[p0 + 1], q1);
    atomicAdd(&sp1[p0 + 2], s2); atomicAdd(&sq1[p0 + 2], q2);
    atomicAdd(&sp1[p0 + 3], s3); atomicAdd(&sq1[p0 + 3], q3);
    __syncthreads();

    // ---- Stage 2: finalize per-pixel LN stats (128 threads = 128 pixels) ----
    if (t < 128) {
        float mu  = sp1[t] * (1.0f / 256.0f);
        float var = sq1[t] * (1.0f / 256.0f) - mu * mu;
        mu_s[t] = mu;
        rs_s[t] = rsqrtf(var + 1e-5f);
    }
    __syncthreads();

    // ---- Stage 3: pm — thread (c, pt) sums its patch over 64 px ----
    // Pixel p = r8*16 + pt*8 + j (j=0..7) -> word r8*8 + pt*4 + (j>>1).
    // Lanes have consecutive c at fixed word offset -> addr stride 65 words
    // (1 mod 32) -> conflict-free. mu/rs reads are wave-broadcast.
    {
        const int c  = t & 255;
        const int pt = t >> 8;         // patch 0/1
        const __hip_bfloat162* crow = &xl[c * XPITCH + pt * 4];
        float acc = 0.f;
#pragma unroll
        for (int r8 = 0; r8 < 8; ++r8) {
            const int wbase = r8 * 8;              // word base of this row
            const int pbase = r8 * 16 + pt * 8;    // pixel base of this row
#pragma unroll
            for (int j = 0; j < 4; ++j) {
                float2 xy = __bfloat1622float2(crow[wbase + j]);
                const int p = pbase + j * 2;
                acc += rs_s[p]     * (xy.x - mu_s[p])
                     + rs_s[p + 1] * (xy.y - mu_s[p + 1]);
            }
        }
        pm_s[pt * C_DIM + c] = gs[c] * acc * (1.0f / 64.0f) + bs[c];
    }
    __syncthreads();

    // ---- Stage 4a: h = silu(w1 @ pm) for 2 patches; w1 [32][256] row-major ----
    {
        const int pt = t >> 8;         // patch 0/1
        const int r  = (t >> 3) & 31;  // output row
        const int k8 = t & 7;          // 8-way split of the dot
        const float4* wrow = reinterpret_cast<const float4*>(w1 + r * C_DIM + k8 * 32);
        const float* pmk = &pm_s[pt * C_DIM + k8 * 32];
        float s = 0.f;
#pragma unroll
        for (int j = 0; j < 8; ++j) {
            float4 wv = wrow[j];
            float4 pv = *reinterpret_cast<const float4*>(pmk + j * 4);
            s += wv.x * pv.x + wv.y * pv.y + wv.z * pv.z + wv.w * pv.w;
        }
        s += __shfl_down(s, 4, 8);
        s += __shfl_down(s, 2, 8);
        s += __shfl_down(s, 1, 8);
        if (k8 == 0) {
            float sig = 1.0f / (1.0f + __expf(-s));
            h_s[pt * R_DIM + r] = s * sig;
        }
    }
    __syncthreads();

    // ---- Stage 4b: gate = sigmoid(w2 @ h); fold gamma/beta; w2 [256][32] ----
    {
        const int pt = t >> 8;
        const int c4 = t & 255;
        const float4* wrow = reinterpret_cast<const float4*>(w2 + c4 * R_DIM);
        const float* hk = &h_s[pt * R_DIM];
        float s = 0.f;
#pragma unroll
        for (int j = 0; j < 8; ++j) {
            float4 wv = wrow[j];
            s += wv.x * hk[j * 4 + 0] + wv.y * hk[j * 4 + 1]
               + wv.z * hk[j * 4 + 2] + wv.w * hk[j * 4 + 3];
        }
        float gate = 1.0f / (1.0f + __expf(-s));
        AB_s[pt * C_DIM + c4] = make_float2(gs[c4] * gate, bs[c4] * gate);
    }
    __syncthreads();

    // ---- Stage 5: out = A*rs*(x-mu) + B from LDS bf16; plain dense stores ----
    {
        const float4 mu4 = *reinterpret_cast<const float4*>(&mu_s[p0]);
        const float4 rs4 = *reinterpret_cast<const float4*>(&rs_s[p0]);
        float* ob = out + rowoff + c0 * CH_STRIDE;
#pragma unroll
        for (int k = 0; k < 16; ++k) {
            const int c = (int)c0 + k * 16;
            float2 ab = AB_s[pat * C_DIM + c];
            uint2 wv = *reinterpret_cast<const uint2*>(&xl[c * XPITCH + p2w]);
            __hip_bfloat162 lo = *reinterpret_cast<const __hip_bfloat162*>(&wv.x);
            __hip_bfloat162 hi = *reinterpret_cast<const __hip_bfloat162*>(&wv.y);
            float2 xy = __bfloat1622float2(lo);
            float2 zw = __bfloat1622float2(hi);
            float4 o;
            o.x = ab.x * rs4.x * (xy.x - mu4.x) + ab.y;
            o.y = ab.x * rs4.y * (xy.y - mu4.y) + ab.y;
            o.z = ab.x * rs4.z * (zw.x - mu4.z) + ab.y;
            o.w = ab.x * rs4.w * (zw.y - mu4.w) + ab.y;
            *reinterpret_cast<float4*>(ob + (unsigned)(k * 16) * CH_STRIDE) = o;
        }
    }
}

extern "C" void kernel_launch(void* const* d_in, const int* in_sizes, int n_in,
                              void* d_out, int out_size, void* d_ws, size_t ws_size,
                              hipStream_t stream) {
    const float* x     = (const float*)d_in[0];
    const float* gamma = (const float*)d_in[1];
    const float* beta  = (const float*)d_in[2];
    const float* w1    = (const float*)d_in[3];
    const float* w2    = (const float*)d_in[4];
    float* out = (float*)d_out;

    const int B = in_sizes[0] / (C_DIM * HWDIM * HWDIM);   // 8
    const int nwg = B * 512;                               // 4096 two-patch groups

    lpa_fused_kernel<<<nwg, 512, 0, stream>>>(x, gamma, beta, w1, w2, out, nwg);
}